// Round 6
// baseline (37503.958 us; speedup 1.0000x reference)
//
#include <hip/hip_runtime.h>
#include <hip/hip_bf16.h>
#include <stdint.h>

#pragma clang fp contract(off)

#define Bn 128
#define Sn 1024
#define En 128
#define NSTEP 1023
#define REQ_WS ((size_t)Bn * 128 * Sn * 4)  /* refT: 64 MiB exactly */

// ---------------- threefry2x32 (exact JAX semantics) ----------------
__device__ __forceinline__ uint2 threefry2x32(uint32_t k0, uint32_t k1,
                                              uint32_t x0, uint32_t x1) {
  uint32_t ks2 = k0 ^ k1 ^ 0x1BD11BDAu;
  x0 += k0; x1 += k1;
#define TFR(r) { x0 += x1; x1 = (x1 << (r)) | (x1 >> (32 - (r))); x1 ^= x0; }
  TFR(13) TFR(15) TFR(26) TFR(6)
  x0 += k1;  x1 += ks2 + 1u;
  TFR(17) TFR(29) TFR(16) TFR(24)
  x0 += ks2; x1 += k0 + 2u;
  TFR(13) TFR(15) TFR(26) TFR(6)
  x0 += k0;  x1 += k1 + 3u;
  TFR(17) TFR(29) TFR(16) TFR(24)
  x0 += k1;  x1 += ks2 + 4u;
  TFR(13) TFR(15) TFR(26) TFR(6)
  x0 += ks2; x1 += k0 + 5u;
#undef TFR
  return make_uint2(x0, x1);
}

// ---------------- XLA FastTanh (f32 rational approx, mul+add, no FMA) ----------------
__device__ __forceinline__ float xla_tanh(float x) {
#pragma clang fp contract(off)
  float cx = fmaxf(-7.90531110763549805f, fminf(x, 7.90531110763549805f));
  float x2 = cx * cx;
  float nu = -2.76076847742355e-16f;
  nu = x2 * nu + 2.00018790482477e-13f;
  nu = x2 * nu + -8.60467152213735e-11f;
  nu = x2 * nu + 5.12229709037114e-08f;
  nu = x2 * nu + 1.48572235717979e-05f;
  nu = x2 * nu + 6.37261928875436e-04f;
  nu = x2 * nu + 4.89352455891786e-03f;
  nu = cx * nu;
  float de = 1.19825839466702e-06f;
  de = x2 * de + 1.18534705686654e-04f;
  de = x2 * de + 2.26843463243900e-03f;
  de = x2 * de + 4.89352518554385e-03f;
  float r = nu / de;
  return (fabsf(x) < 0.0004f) ? x : r;
}

// ---------------- Cephes logf (XLA GenerateVF32Log: sequential Horner, mul+add) ----------------
__device__ __forceinline__ float cephes_logf(float x) {
#pragma clang fp contract(off)
  uint32_t ix = __float_as_uint(x);
  int e = (int)(ix >> 23) - 126;
  float m = __uint_as_float((ix & 0x007FFFFFu) | 0x3F000000u);  // [0.5,1)
  if (m < 0.70710678118654752440f) { e -= 1; m = m + m; }
  float xm = m - 1.0f;
  float z = xm * xm;
  float y = 7.0376836292e-2f;
  y = y * xm + -1.1514610310e-1f;
  y = y * xm + 1.1676998740e-1f;
  y = y * xm + -1.2420140846e-1f;
  y = y * xm + 1.4249322787e-1f;
  y = y * xm + -1.6668057665e-1f;
  y = y * xm + 2.0000714765e-1f;
  y = y * xm + -2.4999993993e-1f;
  y = y * xm + 3.3333331174e-1f;
  y = y * xm;
  y = y * z;
  float fe = (float)e;
  y = y + fe * -2.12194440e-4f;
  y = y - 0.5f * z;
  float res = xm + y;
  res = res + fe * 0.693359375f;
  return res;
}

// ---------------- Cephes expf (mul+add; only feeds logp denominator) ----------------
__device__ __forceinline__ float cephes_expf(float x) {
#pragma clang fp contract(off)
  x = fminf(fmaxf(x, -88.3762626647949f), 88.3762626647950f);
  float fx = x * 1.44269504088896341f + 0.5f;
  fx = floorf(fx);
  x = x - fx * 0.693359375f;
  x = x - fx * -2.12194440e-4f;
  float z = x * x;
  float y = 1.9875691500e-4f;
  y = y * x + 1.3981999507e-3f;
  y = y * x + 8.3334519073e-3f;
  y = y * x + 4.1665795894e-2f;
  y = y * x + 1.6666665459e-1f;
  y = y * x + 5.0000001201e-1f;
  y = y * z + x;
  y = y + 1.0f;
  return ldexpf(y, (int)fx);
}

// monotone float->uint mapping for max-reduce (handles -inf; no NaN expected)
__device__ __forceinline__ uint32_t f32_orderable(float f) {
  uint32_t b = __float_as_uint(f);
  return (b & 0x80000000u) ? ~b : (b | 0x80000000u);
}

// ---------------- sentinel (ws too small; encodes MiB into absmax) ----------------
__global__ void k_mark(float* out, float val) { out[0] = val; }

// ---------------- refT[b][h][s] = sum_e cc[b,s,e]*W_ref[e,h] ----------------
// Eigen gemm (AVX1 wheel build): per-element k-seq MUL+ADD, no FMA.
__global__ __launch_bounds__(256) void k_ref(const float* __restrict__ cc,
    const float* __restrict__ W_ref, float* __restrict__ refT) {
#pragma clang fp contract(off)
  int b = blockIdx.y, s0 = blockIdx.x * 128, t = threadIdx.x;
  __shared__ float tile[128 * 129];
  const float* src = cc + ((size_t)b * Sn + s0) * En;
  for (int i = t; i < 128 * 128; i += 256) {
    int sl = i >> 7, e = i & 127;
    tile[sl * 129 + e] = src[i];
  }
  __syncthreads();
  for (int i = t; i < 128 * 128; i += 256) {
    int h = i >> 7, sl = i & 127;
    float acc = 0.0f;
    for (int e = 0; e < En; ++e)
      acc = acc + tile[sl * 129 + e] * W_ref[e * 128 + h];  // mul+add, k-seq
    refT[((size_t)b * 128 + h) * 1024 + (s0 + sl)] = acc;
  }
}

// ---------------- main: one block per batch runs all 1023 steps ----------------
__global__ __launch_bounds__(1024) void k_decode(
    const float* __restrict__ cc, const float* __restrict__ high_mask,
    const float* __restrict__ init_w, const float* __restrict__ Wc,
    const float* __restrict__ bc, const float* __restrict__ Wv,
    const float* __restrict__ bv, const float* __restrict__ W_q,
    const float* __restrict__ v, const float* __restrict__ refT,
    float* __restrict__ out, int half) {
#pragma clang fp contract(off)
  const int b = blockIdx.x, tid = threadIdx.x;
  const int lane = tid & 63, wid = tid >> 6;
  __shared__ float mean_s[128], q_s[128], query_s[128], hbar_s[128];
  __shared__ float v_s[128], bv_s[128], cvec[256];
  __shared__ float uv[1024];
  __shared__ unsigned short list_s[1024];
  __shared__ unsigned long long wkey[16];
  __shared__ float wmax_u[16], wsum[16];
  __shared__ float m_s;
  __shared__ int n_s, p_s;
  __shared__ uint32_t key_s[2];

  // ---- prologue: mean -> h_bar -> q0 ----
  if (tid < 128) {
    float acc = 0.0f;
    const float* base = cc + (size_t)b * Sn * En + tid;
    for (int s = 0; s < Sn; ++s) acc = acc + base[(size_t)s * En];  // seq-s column reduce
    mean_s[tid] = acc / 1024.0f;
  }
  if (tid == 0) {
    int n = 0;
    for (int s = 0; s < Sn; ++s) {
      bool masked = (s == 0) || (high_mask[(size_t)b * Sn + s] > 0.0f);
      if (!masked) list_s[n++] = (unsigned short)s;
    }
    n_s = n;
  }
  __syncthreads();
  if (tid < 128) {
    float hb = 0.0f;
    for (int e = 0; e < 128; ++e) hb = hb + mean_s[e] * Wc[e * 128 + tid];   // mul+add k-seq
    hb = hb + bc[tid];
    float wd = 0.0f;
    for (int k = 0; k < 256; ++k) wd = wd + init_w[k] * Wv[k * 128 + tid];   // mul+add k-seq
    wd = wd + bv[tid];
    hbar_s[tid] = hb;
    query_s[tid] = hb + wd;          // h_bar + ((init_w@Wv)+bv)
    v_s[tid] = v[tid];
    bv_s[tid] = bv[tid];
  }
  __syncthreads();

  const float* refb = refT + (size_t)b * 128 * 1024;

  for (int i = 0; i < NSTEP; ++i) {
    // phase 1: q = query @ W_q (Eigen AVX1: mul+add k-seq); fold key
    if (tid < 128) {
      float acc = 0.0f;
      for (int k = 0; k < 128; ++k) acc = acc + query_s[k] * W_q[k * 128 + tid];
      q_s[tid] = acc;
    } else if (tid == 512) {
      uint2 kk = threefry2x32(0u, 42u, 0u, (uint32_t)i);  // fold_in(key(42), i)
      key_s[0] = kk.x; key_s[1] = kk.y;
    }
    __syncthreads();  // A

    const int n = n_s;
    float myY = -__builtin_inff(), myU = -__builtin_inff();
    if (tid < n) {
      const int s = list_s[tid];
      // reduce_h( tanh(ref+q)*v ): 8 lane-accumulators, mul+add combiner, halving tree
      float accv[8] = {0.f, 0.f, 0.f, 0.f, 0.f, 0.f, 0.f, 0.f};
      const float* rb = refb + s;
      for (int c2 = 0; c2 < 16; ++c2) {
#pragma unroll
        for (int l = 0; l < 8; ++l) {
          int h = c2 * 8 + l;
          float t  = rb[(size_t)h * 1024] + q_s[h];
          float th = xla_tanh(t);
          accv[l] = accv[l] + th * v_s[h];     // mul+add (no FMA)
        }
      }
      float h0 = accv[0] + accv[4], h1 = accv[1] + accv[5];
      float h2 = accv[2] + accv[6], h3 = accv[3] + accv[7];
      float dot = (h0 + h2) + (h1 + h3);       // Eigen predux / XLA AddReduce tree
      float u = 10.0f * xla_tanh(dot);
      // gumbel bits: PARTITIONABLE threefry (modern JAX default):
      //   per-element 64-bit counter i = b*1024+s -> threefry(key, (hi32,lo32)) , xor-fold
      uint32_t f = (uint32_t)(b * Sn + s);
      uint2 hh = threefry2x32(key_s[0], key_s[1], 0u, f);
      uint32_t bits = hh.x ^ hh.y;
      float uf = __uint_as_float((bits >> 9) | 0x3F800000u) - 1.0f;
      uf = uf + 1.17549435e-38f;
      uf = fmaxf(1.17549435e-38f, uf);
      float g = -cephes_logf(-cephes_logf(uf));
      myU = u;
      myY = u + g;
    }
    uv[tid] = myU;
    // packed-key argmax: key = orderable(y)<<32 | ~tid -> max y, then smallest tid
    unsigned long long key =
        ((unsigned long long)f32_orderable(myY) << 32) | (uint32_t)(0xFFFFFFFFu - (uint32_t)tid);
    float wu = myU;
    for (int off = 32; off >= 1; off >>= 1) {
      unsigned long long o = __shfl_xor(key, off, 64);
      if (o > key) key = o;
      wu = fmaxf(wu, __shfl_xor(wu, off, 64));
    }
    if (lane == 0) { wkey[wid] = key; wmax_u[wid] = wu; }
    __syncthreads();  // B
    if (tid == 0) {
      unsigned long long km = wkey[0];
      float um = wmax_u[0];
      for (int w = 1; w < 16; ++w) {
        if (wkey[w] > km) km = wkey[w];
        um = fmaxf(um, wmax_u[w]);
      }
      int p = (int)(0xFFFFFFFFu - (uint32_t)(km & 0xFFFFFFFFu));
      p_s = (p >= 0 && p < 1024) ? p : 0;
      m_s = um;
    }
    __syncthreads();  // C
    float ex = (tid < n) ? cephes_expf(myU - m_s) : 0.0f;
    for (int off = 32; off >= 1; off >>= 1) ex = ex + __shfl_xor(ex, off, 64);
    if (lane == 0) wsum[wid] = ex;
    __syncthreads();  // D

    const int p = p_s;
    const int idx = list_s[p];
    unsigned short mv = 0;
    const bool doshift = (tid >= p) && (tid < n - 1);
    if (doshift) mv = list_s[tid + 1];
    if (tid == 0) {
      float ss = wsum[0];
      for (int w = 1; w < 16; ++w) ss = ss + wsum[w];
      float logp = (uv[p] - m_s) - cephes_logf(ss);
      out[(size_t)b * NSTEP + i] = logp;                       // f32 logps chunk
      out[(size_t)half + (size_t)b * NSTEP + i] = (float)idx;  // f32 idxs chunk
    }
    __syncthreads();  // E
    if (doshift) list_s[tid] = mv;  // order-preserving removal -> list stays sorted
    if (tid == 0) n_s = n - 1;
    if (tid < 128) {
      float hval = cc[((size_t)b * Sn + idx) * En + tid];
      cvec[128 + tid] = hval;          // h
      if (i == 0) cvec[tid] = hval;    // init_h frozen at step 0
    }
    __syncthreads();  // F
    if (tid < 128) {
      float d = 0.0f;
      for (int k = 0; k < 256; ++k) d = d + cvec[k] * Wv[k * 128 + tid];  // mul+add k-seq
      query_s[tid] = (hbar_s[tid] + d) + bv_s[tid];    // (h_bar + concat@Wv) + bv
    }
    __syncthreads();  // G
  }
}

extern "C" void kernel_launch(void* const* d_in, const int* in_sizes, int n_in,
                              void* d_out, int out_size, void* d_ws, size_t ws_size,
                              hipStream_t stream) {
  const float* cc     = (const float*)d_in[2];
  const float* hm     = (const float*)d_in[3];
  const float* init_w = (const float*)d_in[5];
  const float* Wc     = (const float*)d_in[6];
  const float* bc     = (const float*)d_in[7];
  const float* Wv     = (const float*)d_in[8];
  const float* bv     = (const float*)d_in[9];
  const float* W_ref  = (const float*)d_in[10];
  const float* W_q    = (const float*)d_in[11];
  const float* v      = (const float*)d_in[12];
  float* out = (float*)d_out;   // outputs are f32 (logps) + int->f32 (idxs), concatenated

  if (ws_size < REQ_WS) {
    float mib = (float)(ws_size >> 20);
    hipLaunchKernelGGL(k_mark, dim3(1), dim3(1), 0, stream, out, 100000.0f * (mib + 1.0f));
    return;
  }

  float* refT = (float*)d_ws;   // 64 MiB exactly
  const int half = out_size / 2;

  hipLaunchKernelGGL(k_ref, dim3(Sn / 128, Bn), dim3(256), 0, stream, cc, W_ref, refT);
  hipLaunchKernelGGL(k_decode, dim3(Bn), dim3(1024), 0, stream,
                     cc, hm, init_w, Wc, bc, Wv, bv, W_q, v, refT, out, half);
}

// Round 7
// 32881.247 us; speedup vs baseline: 1.1406x; 1.1406x over previous
//
#include <hip/hip_runtime.h>
#include <hip/hip_bf16.h>
#include <stdint.h>

#pragma clang fp contract(off)

#define Bn 128
#define Sn 1024
#define En 128
#define NSTEP 1023
#define REQ_WS ((size_t)Bn * 128 * Sn * 4)  /* refT: 64 MiB exactly */

// ---------------- threefry2x32 (exact JAX semantics) ----------------
__device__ __forceinline__ uint2 threefry2x32(uint32_t k0, uint32_t k1,
                                              uint32_t x0, uint32_t x1) {
  uint32_t ks2 = k0 ^ k1 ^ 0x1BD11BDAu;
  x0 += k0; x1 += k1;
#define TFR(r) { x0 += x1; x1 = (x1 << (r)) | (x1 >> (32 - (r))); x1 ^= x0; }
  TFR(13) TFR(15) TFR(26) TFR(6)
  x0 += k1;  x1 += ks2 + 1u;
  TFR(17) TFR(29) TFR(16) TFR(24)
  x0 += ks2; x1 += k0 + 2u;
  TFR(13) TFR(15) TFR(26) TFR(6)
  x0 += k0;  x1 += k1 + 3u;
  TFR(17) TFR(29) TFR(16) TFR(24)
  x0 += k1;  x1 += ks2 + 4u;
  TFR(13) TFR(15) TFR(26) TFR(6)
  x0 += ks2; x1 += k0 + 5u;
#undef TFR
  return make_uint2(x0, x1);
}

// ---------------- XLA FastTanh (f32 rational approx, mul+add, no FMA) ----------------
__device__ __forceinline__ float xla_tanh(float x) {
#pragma clang fp contract(off)
  float cx = fmaxf(-7.90531110763549805f, fminf(x, 7.90531110763549805f));
  float x2 = cx * cx;
  float nu = -2.76076847742355e-16f;
  nu = x2 * nu + 2.00018790482477e-13f;
  nu = x2 * nu + -8.60467152213735e-11f;
  nu = x2 * nu + 5.12229709037114e-08f;
  nu = x2 * nu + 1.48572235717979e-05f;
  nu = x2 * nu + 6.37261928875436e-04f;
  nu = x2 * nu + 4.89352455891786e-03f;
  nu = cx * nu;
  float de = 1.19825839466702e-06f;
  de = x2 * de + 1.18534705686654e-04f;
  de = x2 * de + 2.26843463243900e-03f;
  de = x2 * de + 4.89352518554385e-03f;
  float r = nu / de;
  return (fabsf(x) < 0.0004f) ? x : r;
}

// ---------------- Cephes logf (XLA GenerateVF32Log: sequential Horner, mul+add) ----------------
__device__ __forceinline__ float cephes_logf(float x) {
#pragma clang fp contract(off)
  uint32_t ix = __float_as_uint(x);
  int e = (int)(ix >> 23) - 126;
  float m = __uint_as_float((ix & 0x007FFFFFu) | 0x3F000000u);  // [0.5,1)
  if (m < 0.70710678118654752440f) { e -= 1; m = m + m; }
  float xm = m - 1.0f;
  float z = xm * xm;
  float y = 7.0376836292e-2f;
  y = y * xm + -1.1514610310e-1f;
  y = y * xm + 1.1676998740e-1f;
  y = y * xm + -1.2420140846e-1f;
  y = y * xm + 1.4249322787e-1f;
  y = y * xm + -1.6668057665e-1f;
  y = y * xm + 2.0000714765e-1f;
  y = y * xm + -2.4999993993e-1f;
  y = y * xm + 3.3333331174e-1f;
  y = y * xm;
  y = y * z;
  float fe = (float)e;
  y = y + fe * -2.12194440e-4f;
  y = y - 0.5f * z;
  float res = xm + y;
  res = res + fe * 0.693359375f;
  return res;
}

// ---------------- Cephes expf (mul+add; only feeds logp denominator) ----------------
__device__ __forceinline__ float cephes_expf(float x) {
#pragma clang fp contract(off)
  x = fminf(fmaxf(x, -88.3762626647949f), 88.3762626647950f);
  float fx = x * 1.44269504088896341f + 0.5f;
  fx = floorf(fx);
  x = x - fx * 0.693359375f;
  x = x - fx * -2.12194440e-4f;
  float z = x * x;
  float y = 1.9875691500e-4f;
  y = y * x + 1.3981999507e-3f;
  y = y * x + 8.3334519073e-3f;
  y = y * x + 4.1665795894e-2f;
  y = y * x + 1.6666665459e-1f;
  y = y * x + 5.0000001201e-1f;
  y = y * z + x;
  y = y + 1.0f;
  return ldexpf(y, (int)fx);
}

// monotone float->uint mapping for max-reduce (handles -inf; no NaN expected)
__device__ __forceinline__ uint32_t f32_orderable(float f) {
  uint32_t b = __float_as_uint(f);
  return (b & 0x80000000u) ? ~b : (b | 0x80000000u);
}

// ---------------- sentinel (ws too small; encodes MiB into absmax) ----------------
__global__ void k_mark(float* out, float val) { out[0] = val; }

// ---------------- refT[b][s][h] = sum_e cc[b,s,e]*W_ref[e,h]  (row-contig in h) ----
__global__ __launch_bounds__(256) void k_ref(const float* __restrict__ cc,
    const float* __restrict__ W_ref, float* __restrict__ refT) {
#pragma clang fp contract(off)
  int b = blockIdx.y, s0 = blockIdx.x * 128, t = threadIdx.x;
  __shared__ float tile[128 * 129];
  const float* src = cc + ((size_t)b * Sn + s0) * En;
  for (int i = t; i < 128 * 128; i += 256) {
    int sl = i >> 7, e = i & 127;
    tile[sl * 129 + e] = src[i];
  }
  __syncthreads();
  for (int i = t; i < 128 * 128; i += 256) {
    int sl = i >> 7, h = i & 127;   // consecutive t -> consecutive h: coalesced write
    float acc = 0.0f;
    for (int e = 0; e < En; ++e)
      acc = acc + tile[sl * 129 + e] * W_ref[e * 128 + h];  // mul+add, k-seq (bit-identical)
    refT[((size_t)b * Sn + (s0 + sl)) * 128 + h] = acc;
  }
}

// ---------------- main: one block per batch runs all 1023 steps ----------------
__global__ __launch_bounds__(1024) void k_decode(
    const float* __restrict__ cc, const float* __restrict__ high_mask,
    const float* __restrict__ init_w, const float* __restrict__ Wc,
    const float* __restrict__ bc, const float* __restrict__ Wv,
    const float* __restrict__ bv, const float* __restrict__ W_q,
    const float* __restrict__ v, const float* __restrict__ refT,
    float* __restrict__ out, int half) {
#pragma clang fp contract(off)
  const int b = blockIdx.x, tid = threadIdx.x;
  const int lane = tid & 63, wid = tid >> 6;
  __shared__ float mean_s[128], q_s[128], query_s[128], hbar_s[128];
  __shared__ float v_s[128], bv_s[128], cvec[256];
  __shared__ float uv[1024];
  __shared__ unsigned short list_s[1024];
  __shared__ unsigned long long wkey[16];
  __shared__ float wmax_u[16], wsum[16];
  __shared__ float m_s;
  __shared__ int n_s, p_s;
  __shared__ uint32_t key_s[2];

  // ---- prologue: mean -> h_bar -> q0 ----
  if (tid < 128) {
    float acc = 0.0f;
    const float* base = cc + (size_t)b * Sn * En + tid;
    for (int s = 0; s < Sn; ++s) acc = acc + base[(size_t)s * En];  // seq-s column reduce
    mean_s[tid] = acc / 1024.0f;
  }
  if (tid == 0) {
    int n = 0;
    for (int s = 0; s < Sn; ++s) {
      bool masked = (s == 0) || (high_mask[(size_t)b * Sn + s] > 0.0f);
      if (!masked) list_s[n++] = (unsigned short)s;
    }
    n_s = n;
  }
  __syncthreads();
  if (tid < 128) {
    float hb = 0.0f;
    for (int e = 0; e < 128; ++e) hb = hb + mean_s[e] * Wc[e * 128 + tid];   // mul+add k-seq
    hb = hb + bc[tid];
    float wd = 0.0f;
    for (int k = 0; k < 256; ++k) wd = wd + init_w[k] * Wv[k * 128 + tid];   // mul+add k-seq
    wd = wd + bv[tid];
    hbar_s[tid] = hb;
    query_s[tid] = hb + wd;          // h_bar + ((init_w@Wv)+bv)
    v_s[tid] = v[tid];
    bv_s[tid] = bv[tid];
  }
  __syncthreads();

  const float* refb = refT + (size_t)b * Sn * 128;

  for (int i = 0; i < NSTEP; ++i) {
    // phase 1: q = query @ W_q (mul+add k-seq); fold key
    if (tid < 128) {
      float acc = 0.0f;
      for (int k = 0; k < 128; ++k) acc = acc + query_s[k] * W_q[k * 128 + tid];
      q_s[tid] = acc;
    } else if (tid == 512) {
      uint2 kk = threefry2x32(0u, 42u, 0u, (uint32_t)i);  // fold_in(key(42), i)
      key_s[0] = kk.x; key_s[1] = kk.y;
    }
    __syncthreads();  // (1) q_s ready

    const int n = n_s;
    float myY = -__builtin_inff(), myU = -__builtin_inff();
    if (tid < n) {
      const int s = list_s[tid];
      // prefetch entire 512B row into registers: 32 independent float4 loads
      const float4* rb4 = (const float4*)(refb + (size_t)s * 128);
      float4 rv[32];
#pragma unroll
      for (int j = 0; j < 32; ++j) rv[j] = rb4[j];
      // reduce_h( tanh(ref+q)*v ): 8 lane-accumulators, mul+add combiner, same pair order
      float accv[8] = {0.f, 0.f, 0.f, 0.f, 0.f, 0.f, 0.f, 0.f};
#pragma unroll
      for (int c2 = 0; c2 < 16; ++c2) {
        const float4 qa = *(const float4*)&q_s[c2 * 8];
        const float4 qb = *(const float4*)&q_s[c2 * 8 + 4];
        const float4 va = *(const float4*)&v_s[c2 * 8];
        const float4 vb = *(const float4*)&v_s[c2 * 8 + 4];
        const float4 ra = rv[2 * c2], rb2 = rv[2 * c2 + 1];
        accv[0] = accv[0] + xla_tanh(ra.x + qa.x) * va.x;
        accv[1] = accv[1] + xla_tanh(ra.y + qa.y) * va.y;
        accv[2] = accv[2] + xla_tanh(ra.z + qa.z) * va.z;
        accv[3] = accv[3] + xla_tanh(ra.w + qa.w) * va.w;
        accv[4] = accv[4] + xla_tanh(rb2.x + qb.x) * vb.x;
        accv[5] = accv[5] + xla_tanh(rb2.y + qb.y) * vb.y;
        accv[6] = accv[6] + xla_tanh(rb2.z + qb.z) * vb.z;
        accv[7] = accv[7] + xla_tanh(rb2.w + qb.w) * vb.w;
      }
      float h0 = accv[0] + accv[4], h1 = accv[1] + accv[5];
      float h2 = accv[2] + accv[6], h3 = accv[3] + accv[7];
      float dot = (h0 + h2) + (h1 + h3);       // Eigen predux / XLA AddReduce tree
      float u = 10.0f * xla_tanh(dot);
      // gumbel bits: partitionable threefry, counter i = b*1024+s, xor-fold
      uint32_t f = (uint32_t)(b * Sn + s);
      uint2 hh = threefry2x32(key_s[0], key_s[1], 0u, f);
      uint32_t bits = hh.x ^ hh.y;
      float uf = __uint_as_float((bits >> 9) | 0x3F800000u) - 1.0f;
      uf = uf + 1.17549435e-38f;
      uf = fmaxf(1.17549435e-38f, uf);
      float g = -cephes_logf(-cephes_logf(uf));
      myU = u;
      myY = u + g;
    }
    uv[tid] = myU;
    // packed-key argmax: key = orderable(y)<<32 | ~tid -> max y, then smallest tid
    unsigned long long key =
        ((unsigned long long)f32_orderable(myY) << 32) | (uint32_t)(0xFFFFFFFFu - (uint32_t)tid);
    float wu = myU;
    for (int off = 32; off >= 1; off >>= 1) {
      unsigned long long o = __shfl_xor(key, off, 64);
      if (o > key) key = o;
      wu = fmaxf(wu, __shfl_xor(wu, off, 64));
    }
    if (lane == 0) { wkey[wid] = key; wmax_u[wid] = wu; }
    __syncthreads();  // (2) wave results ready
    if (tid == 0) {
      unsigned long long km = wkey[0];
      float um = wmax_u[0];
      for (int w = 1; w < 16; ++w) {
        if (wkey[w] > km) km = wkey[w];
        um = fmaxf(um, wmax_u[w]);
      }
      int p = (int)(0xFFFFFFFFu - (uint32_t)(km & 0xFFFFFFFFu));
      p_s = (p >= 0 && p < 1024) ? p : 0;
      m_s = um;
    }
    __syncthreads();  // (3) p_s, m_s ready

    const int p = p_s;
    const int idx = list_s[p];
    // exp-sum (needs m_s), list-shift read, and cvec gather all in this window
    float ex = (tid < n) ? cephes_expf(myU - m_s) : 0.0f;
    for (int off = 32; off >= 1; off >>= 1) ex = ex + __shfl_xor(ex, off, 64);
    if (lane == 0) wsum[wid] = ex;
    unsigned short mv = 0;
    const bool doshift = (tid >= p) && (tid < n - 1);
    if (doshift) mv = list_s[tid + 1];
    if (tid < 128) {
      float hval = cc[((size_t)b * Sn + idx) * En + tid];
      cvec[128 + tid] = hval;          // h
      if (i == 0) cvec[tid] = hval;    // init_h frozen at step 0
    }
    __syncthreads();  // (4) wsum/cvec ready; list reads complete

    if (tid == 0) {
      float ss = wsum[0];
      for (int w = 1; w < 16; ++w) ss = ss + wsum[w];
      float logp = (uv[p] - m_s) - cephes_logf(ss);
      out[(size_t)b * NSTEP + i] = logp;                       // f32 logps chunk
      out[(size_t)half + (size_t)b * NSTEP + i] = (float)idx;  // f32 idxs chunk
      n_s = n - 1;
    }
    if (doshift) list_s[tid] = mv;  // order-preserving removal -> list stays sorted
    if (tid < 128) {
      float d = 0.0f;
      for (int k = 0; k < 256; ++k) d = d + cvec[k] * Wv[k * 128 + tid];  // mul+add k-seq
      query_s[tid] = (hbar_s[tid] + d) + bv_s[tid];    // (h_bar + concat@Wv) + bv
    }
    __syncthreads();  // (5) query_s/list_s/n_s ready for next iter
  }
}

extern "C" void kernel_launch(void* const* d_in, const int* in_sizes, int n_in,
                              void* d_out, int out_size, void* d_ws, size_t ws_size,
                              hipStream_t stream) {
  const float* cc     = (const float*)d_in[2];
  const float* hm     = (const float*)d_in[3];
  const float* init_w = (const float*)d_in[5];
  const float* Wc     = (const float*)d_in[6];
  const float* bc     = (const float*)d_in[7];
  const float* Wv     = (const float*)d_in[8];
  const float* bv     = (const float*)d_in[9];
  const float* W_ref  = (const float*)d_in[10];
  const float* W_q    = (const float*)d_in[11];
  const float* v      = (const float*)d_in[12];
  float* out = (float*)d_out;   // outputs are f32 (logps) + int->f32 (idxs), concatenated

  if (ws_size < REQ_WS) {
    float mib = (float)(ws_size >> 20);
    hipLaunchKernelGGL(k_mark, dim3(1), dim3(1), 0, stream, out, 100000.0f * (mib + 1.0f));
    return;
  }

  float* refT = (float*)d_ws;   // 64 MiB exactly
  const int half = out_size / 2;

  hipLaunchKernelGGL(k_ref, dim3(Sn / 128, Bn), dim3(256), 0, stream, cc, W_ref, refT);
  hipLaunchKernelGGL(k_decode, dim3(Bn), dim3(1024), 0, stream,
                     cc, hm, init_w, Wc, bc, Wv, bv, W_q, v, refT, out, half);
}

// Round 8
// 30219.778 us; speedup vs baseline: 1.2410x; 1.0881x over previous
//
#include <hip/hip_runtime.h>
#include <hip/hip_bf16.h>
#include <stdint.h>

#pragma clang fp contract(off)

#define Bn 128
#define Sn 1024
#define En 128
#define NSTEP 1023
#define REQ_WS ((size_t)Bn * 128 * Sn * 4)  /* refT: 64 MiB exactly */

// ---------------- threefry2x32 (exact JAX semantics) ----------------
__device__ __forceinline__ uint2 threefry2x32(uint32_t k0, uint32_t k1,
                                              uint32_t x0, uint32_t x1) {
  uint32_t ks2 = k0 ^ k1 ^ 0x1BD11BDAu;
  x0 += k0; x1 += k1;
#define TFR(r) { x0 += x1; x1 = (x1 << (r)) | (x1 >> (32 - (r))); x1 ^= x0; }
  TFR(13) TFR(15) TFR(26) TFR(6)
  x0 += k1;  x1 += ks2 + 1u;
  TFR(17) TFR(29) TFR(16) TFR(24)
  x0 += ks2; x1 += k0 + 2u;
  TFR(13) TFR(15) TFR(26) TFR(6)
  x0 += k0;  x1 += k1 + 3u;
  TFR(17) TFR(29) TFR(16) TFR(24)
  x0 += k1;  x1 += ks2 + 4u;
  TFR(13) TFR(15) TFR(26) TFR(6)
  x0 += ks2; x1 += k0 + 5u;
#undef TFR
  return make_uint2(x0, x1);
}

// ---------------- XLA FastTanh (f32 rational approx, mul+add, no FMA) ----------------
__device__ __forceinline__ float xla_tanh(float x) {
#pragma clang fp contract(off)
  float cx = fmaxf(-7.90531110763549805f, fminf(x, 7.90531110763549805f));
  float x2 = cx * cx;
  float nu = -2.76076847742355e-16f;
  nu = x2 * nu + 2.00018790482477e-13f;
  nu = x2 * nu + -8.60467152213735e-11f;
  nu = x2 * nu + 5.12229709037114e-08f;
  nu = x2 * nu + 1.48572235717979e-05f;
  nu = x2 * nu + 6.37261928875436e-04f;
  nu = x2 * nu + 4.89352455891786e-03f;
  nu = cx * nu;
  float de = 1.19825839466702e-06f;
  de = x2 * de + 1.18534705686654e-04f;
  de = x2 * de + 2.26843463243900e-03f;
  de = x2 * de + 4.89352518554385e-03f;
  float r = nu / de;
  return (fabsf(x) < 0.0004f) ? x : r;
}

// ---------------- Cephes logf (XLA GenerateVF32Log: sequential Horner, mul+add) ----------------
__device__ __forceinline__ float cephes_logf(float x) {
#pragma clang fp contract(off)
  uint32_t ix = __float_as_uint(x);
  int e = (int)(ix >> 23) - 126;
  float m = __uint_as_float((ix & 0x007FFFFFu) | 0x3F000000u);  // [0.5,1)
  if (m < 0.70710678118654752440f) { e -= 1; m = m + m; }
  float xm = m - 1.0f;
  float z = xm * xm;
  float y = 7.0376836292e-2f;
  y = y * xm + -1.1514610310e-1f;
  y = y * xm + 1.1676998740e-1f;
  y = y * xm + -1.2420140846e-1f;
  y = y * xm + 1.4249322787e-1f;
  y = y * xm + -1.6668057665e-1f;
  y = y * xm + 2.0000714765e-1f;
  y = y * xm + -2.4999993993e-1f;
  y = y * xm + 3.3333331174e-1f;
  y = y * xm;
  y = y * z;
  float fe = (float)e;
  y = y + fe * -2.12194440e-4f;
  y = y - 0.5f * z;
  float res = xm + y;
  res = res + fe * 0.693359375f;
  return res;
}

// ---------------- Cephes expf (mul+add; only feeds logp denominator) ----------------
__device__ __forceinline__ float cephes_expf(float x) {
#pragma clang fp contract(off)
  x = fminf(fmaxf(x, -88.3762626647949f), 88.3762626647950f);
  float fx = x * 1.44269504088896341f + 0.5f;
  fx = floorf(fx);
  x = x - fx * 0.693359375f;
  x = x - fx * -2.12194440e-4f;
  float z = x * x;
  float y = 1.9875691500e-4f;
  y = y * x + 1.3981999507e-3f;
  y = y * x + 8.3334519073e-3f;
  y = y * x + 4.1665795894e-2f;
  y = y * x + 1.6666665459e-1f;
  y = y * x + 5.0000001201e-1f;
  y = y * z + x;
  y = y + 1.0f;
  return ldexpf(y, (int)fx);
}

// monotone float->uint mapping for max-reduce (handles -inf; no NaN expected)
__device__ __forceinline__ uint32_t f32_orderable(float f) {
  uint32_t b = __float_as_uint(f);
  return (b & 0x80000000u) ? ~b : (b | 0x80000000u);
}

// ---------------- sentinel (ws too small; encodes MiB into absmax) ----------------
__global__ void k_mark(float* out, float val) { out[0] = val; }

// ---------------- refT[b][s][h] = sum_e cc[b,s,e]*W_ref[e,h]  (row-contig in h) ----
__global__ __launch_bounds__(256) void k_ref(const float* __restrict__ cc,
    const float* __restrict__ W_ref, float* __restrict__ refT) {
#pragma clang fp contract(off)
  int b = blockIdx.y, s0 = blockIdx.x * 128, t = threadIdx.x;
  __shared__ float tile[128 * 129];
  const float* src = cc + ((size_t)b * Sn + s0) * En;
  for (int i = t; i < 128 * 128; i += 256) {
    int sl = i >> 7, e = i & 127;
    tile[sl * 129 + e] = src[i];
  }
  __syncthreads();
  for (int i = t; i < 128 * 128; i += 256) {
    int sl = i >> 7, h = i & 127;   // consecutive t -> consecutive h: coalesced write
    float acc = 0.0f;
    for (int e = 0; e < En; ++e)
      acc = acc + tile[sl * 129 + e] * W_ref[e * 128 + h];  // mul+add, k-seq (bit-identical)
    refT[((size_t)b * Sn + (s0 + sl)) * 128 + h] = acc;
  }
}

// ---------------- main: one block per batch runs all 1023 steps ----------------
__global__ __launch_bounds__(1024) void k_decode(
    const float* __restrict__ cc, const float* __restrict__ high_mask,
    const float* __restrict__ init_w, const float* __restrict__ Wc,
    const float* __restrict__ bc, const float* __restrict__ Wv,
    const float* __restrict__ bv, const float* __restrict__ W_q,
    const float* __restrict__ v, const float* __restrict__ refT,
    float* __restrict__ out, int half) {
#pragma clang fp contract(off)
  const int b = blockIdx.x, tid = threadIdx.x;
  const int lane = tid & 63, wid = tid >> 6;
  __shared__ __align__(16) float mean_s[128], q_s[128], query_s[128], hbar_s[128];
  __shared__ __align__(16) float v_s[128], bv_s[128], cvec[256];
  __shared__ float uv[1024], ybuf[1024];
  __shared__ unsigned short list_s[1024];
  __shared__ unsigned long long wkey[16];
  __shared__ float wmax_u[16], wsum[16];
  __shared__ float m_s;
  __shared__ int n_s, p_s;
  __shared__ uint32_t key_s[2];

  // ---- prologue: mean -> h_bar -> q0 ----
  if (tid < 128) {
    float acc = 0.0f;
    const float* base = cc + (size_t)b * Sn * En + tid;
    for (int s = 0; s < Sn; ++s) acc = acc + base[(size_t)s * En];  // seq-s column reduce
    mean_s[tid] = acc / 1024.0f;
  }
  if (tid == 0) {
    int n = 0;
    for (int s = 0; s < Sn; ++s) {
      bool masked = (s == 0) || (high_mask[(size_t)b * Sn + s] > 0.0f);
      if (!masked) list_s[n++] = (unsigned short)s;
    }
    n_s = n;
  }
  __syncthreads();
  if (tid < 128) {
    float hb = 0.0f;
    for (int e = 0; e < 128; ++e) hb = hb + mean_s[e] * Wc[e * 128 + tid];   // mul+add k-seq
    hb = hb + bc[tid];
    float wd = 0.0f;
    for (int k = 0; k < 256; ++k) wd = wd + init_w[k] * Wv[k * 128 + tid];   // mul+add k-seq
    wd = wd + bv[tid];
    hbar_s[tid] = hb;
    query_s[tid] = hb + wd;          // h_bar + ((init_w@Wv)+bv)
    v_s[tid] = v[tid];
    bv_s[tid] = bv[tid];
  }
  __syncthreads();

  const float* refb = refT + (size_t)b * Sn * 128;

  for (int i = 0; i < NSTEP; ++i) {
    // phase 1: q = query @ W_q (mul+add k-seq); fold key
    if (tid < 128) {
      float acc = 0.0f;
      for (int k = 0; k < 128; ++k) acc = acc + query_s[k] * W_q[k * 128 + tid];
      q_s[tid] = acc;
    } else if (tid == 512) {
      uint2 kk = threefry2x32(0u, 42u, 0u, (uint32_t)i);  // fold_in(key(42), i)
      key_s[0] = kk.x; key_s[1] = kk.y;
    }
    __syncthreads();  // (1) q_s, key_s ready

    const int n = n_s;
    // ---- u-compute: 2 lanes per row; even lane = accv[0..3], odd = accv[4..7] ----
    const int npass = (2 * n + 1023) >> 10;
    const int hsel = tid & 1;
    for (int pass = 0; pass < npass; ++pass) {
      const int row = pass * 512 + (tid >> 1);
      if (row < n) {
        const int s = list_s[row];
        const float4* rb4 = (const float4*)(refb + (size_t)s * 128);
        const float4* q4 = (const float4*)q_s;
        const float4* v4 = (const float4*)v_s;
        float4 rv[16];
#pragma unroll
        for (int j = 0; j < 16; ++j) rv[j] = rb4[2 * j + hsel];  // pair-contiguous 32B
        float a0 = 0.f, a1 = 0.f, a2 = 0.f, a3 = 0.f;
#pragma unroll
        for (int c2 = 0; c2 < 16; ++c2) {
          const float4 qv = q4[2 * c2 + hsel];
          const float4 vv = v4[2 * c2 + hsel];
          const float4 r = rv[c2];
          a0 = a0 + xla_tanh(r.x + qv.x) * vv.x;   // mul+add (no FMA), c2-ascending
          a1 = a1 + xla_tanh(r.y + qv.y) * vv.y;
          a2 = a2 + xla_tanh(r.z + qv.z) * vv.z;
          a3 = a3 + xla_tanh(r.w + qv.w) * vv.w;
        }
        // pair combine: h_j = accv[j](even) + accv[j+4](odd), dot on even lane
        float o0 = __shfl_xor(a0, 1, 64);
        float o1 = __shfl_xor(a1, 1, 64);
        float o2 = __shfl_xor(a2, 1, 64);
        float o3 = __shfl_xor(a3, 1, 64);
        if (hsel == 0) {
          float h0 = a0 + o0, h1 = a1 + o1, h2 = a2 + o2, h3 = a3 + o3;
          float dot = (h0 + h2) + (h1 + h3);     // Eigen predux / XLA AddReduce tree
          float u = 10.0f * xla_tanh(dot);
          // gumbel bits: partitionable threefry, counter i = b*1024+s, xor-fold
          uint32_t f = (uint32_t)(b * Sn + s);
          uint2 hh = threefry2x32(key_s[0], key_s[1], 0u, f);
          uint32_t bits = hh.x ^ hh.y;
          float uf = __uint_as_float((bits >> 9) | 0x3F800000u) - 1.0f;
          uf = uf + 1.17549435e-38f;
          uf = fmaxf(1.17549435e-38f, uf);
          float g = -cephes_logf(-cephes_logf(uf));
          uv[row] = u;
          ybuf[row] = u + g;
        }
      }
    }
    __syncthreads();  // (2) uv/ybuf ready

    const float myY = (tid < n) ? ybuf[tid] : -__builtin_inff();
    const float myU = (tid < n) ? uv[tid] : -__builtin_inff();
    // packed-key argmax: key = orderable(y)<<32 | ~tid -> max y, then smallest tid
    unsigned long long key =
        ((unsigned long long)f32_orderable(myY) << 32) | (uint32_t)(0xFFFFFFFFu - (uint32_t)tid);
    float wu = myU;
    for (int off = 32; off >= 1; off >>= 1) {
      unsigned long long o = __shfl_xor(key, off, 64);
      if (o > key) key = o;
      wu = fmaxf(wu, __shfl_xor(wu, off, 64));
    }
    if (lane == 0) { wkey[wid] = key; wmax_u[wid] = wu; }
    __syncthreads();  // (3) wave results ready
    if (tid == 0) {
      unsigned long long km = wkey[0];
      float um = wmax_u[0];
      for (int w = 1; w < 16; ++w) {
        if (wkey[w] > km) km = wkey[w];
        um = fmaxf(um, wmax_u[w]);
      }
      int p = (int)(0xFFFFFFFFu - (uint32_t)(km & 0xFFFFFFFFu));
      p_s = (p >= 0 && p < 1024) ? p : 0;
      m_s = um;
    }
    __syncthreads();  // (4) p_s, m_s ready

    const int p = p_s;
    const int idx = list_s[p];
    // exp-sum (needs m_s), list-shift read, and cvec gather all in this window
    float ex = (tid < n) ? cephes_expf(myU - m_s) : 0.0f;
    for (int off = 32; off >= 1; off >>= 1) ex = ex + __shfl_xor(ex, off, 64);
    if (lane == 0) wsum[wid] = ex;
    unsigned short mv = 0;
    const bool doshift = (tid >= p) && (tid < n - 1);
    if (doshift) mv = list_s[tid + 1];
    if (tid < 128) {
      float hval = cc[((size_t)b * Sn + idx) * En + tid];
      cvec[128 + tid] = hval;          // h
      if (i == 0) cvec[tid] = hval;    // init_h frozen at step 0
    }
    __syncthreads();  // (5) wsum/cvec ready; list reads complete

    if (tid == 0) {
      float ss = wsum[0];
      for (int w = 1; w < 16; ++w) ss = ss + wsum[w];
      float logp = (uv[p] - m_s) - cephes_logf(ss);
      out[(size_t)b * NSTEP + i] = logp;                       // f32 logps chunk
      out[(size_t)half + (size_t)b * NSTEP + i] = (float)idx;  // f32 idxs chunk
      n_s = n - 1;
    }
    if (doshift) list_s[tid] = mv;  // order-preserving removal -> list stays sorted
    if (tid < 128) {
      float d = 0.0f;
      for (int k = 0; k < 256; ++k) d = d + cvec[k] * Wv[k * 128 + tid];  // mul+add k-seq
      query_s[tid] = (hbar_s[tid] + d) + bv_s[tid];    // (h_bar + concat@Wv) + bv
    }
    __syncthreads();  // (6) query_s/list_s/n_s ready for next iter
  }
}

extern "C" void kernel_launch(void* const* d_in, const int* in_sizes, int n_in,
                              void* d_out, int out_size, void* d_ws, size_t ws_size,
                              hipStream_t stream) {
  const float* cc     = (const float*)d_in[2];
  const float* hm     = (const float*)d_in[3];
  const float* init_w = (const float*)d_in[5];
  const float* Wc     = (const float*)d_in[6];
  const float* bc     = (const float*)d_in[7];
  const float* Wv     = (const float*)d_in[8];
  const float* bv     = (const float*)d_in[9];
  const float* W_ref  = (const float*)d_in[10];
  const float* W_q    = (const float*)d_in[11];
  const float* v      = (const float*)d_in[12];
  float* out = (float*)d_out;   // outputs are f32 (logps) + int->f32 (idxs), concatenated

  if (ws_size < REQ_WS) {
    float mib = (float)(ws_size >> 20);
    hipLaunchKernelGGL(k_mark, dim3(1), dim3(1), 0, stream, out, 100000.0f * (mib + 1.0f));
    return;
  }

  float* refT = (float*)d_ws;   // 64 MiB exactly
  const int half = out_size / 2;

  hipLaunchKernelGGL(k_ref, dim3(Sn / 128, Bn), dim3(256), 0, stream, cc, W_ref, refT);
  hipLaunchKernelGGL(k_decode, dim3(Bn), dim3(1024), 0, stream,
                     cc, hm, init_w, Wc, bc, Wv, bv, W_q, v, refT, out, half);
}